// Round 8
// baseline (60.344 us; speedup 1.0000x reference)
//
#include <hip/hip_runtime.h>

#define DIM 4096
#define R 8
// ws layout: G (8x8) at ws[0..63]; P2 (4096 rows x 2 halves x 8) at ws+64
#define P_OFF 64

// ---------------------------------------------------------------------------
// K1: blocks 0,1 = Gram rows 0..3 / 4..7 (dispatched first, overlaps).
// Blocks 2..2049: P2[row][ch][:] = W[row, ch-half] @ A[ch-half, :].
// ALL 24 loads (8 W-float4 + 16 A-float4) issued upfront in one batch;
// __launch_bounds__(256,2) lets VGPR grow so the compiler can keep them
// all in flight instead of interleaving loads with FMAs (R7: VGPR=52).
// ---------------------------------------------------------------------------
__global__ __launch_bounds__(256, 2) void dot_kernel(const float* __restrict__ W,
                                                     const float* __restrict__ A,
                                                     float* __restrict__ G,
                                                     float* __restrict__ P2) {
    __shared__ float red[4][32];
    const int t = threadIdx.x;
    const int wave = t >> 6, lane = t & 63;
    const int bid = blockIdx.x;
    const float4* W4 = (const float4*)W;
    const float4* A4 = (const float4*)A;

    if (bid < 2) {
        // ---- Gram path: block 0 -> G rows 0..3, block 1 -> rows 4..7
        const int hi = bid * 4;  // 0 or 4 (block-uniform)
        float p[4][R];
#pragma unroll
        for (int r = 0; r < 4; ++r)
#pragma unroll
            for (int k = 0; k < R; ++k) p[r][k] = 0.f;

        for (int it = 0; it < DIM / 256; ++it) {
            const int j = it * 256 + t;
            float4 alo = A4[j * 2 + 0];
            float4 ahi = A4[j * 2 + 1];
            float u[R] = {alo.x, alo.y, alo.z, alo.w, ahi.x, ahi.y, ahi.z, ahi.w};
            float wv0 = hi ? u[4] : u[0];
            float wv1 = hi ? u[5] : u[1];
            float wv2 = hi ? u[6] : u[2];
            float wv3 = hi ? u[7] : u[3];
#pragma unroll
            for (int k = 0; k < R; ++k) {
                p[0][k] += wv0 * u[k];
                p[1][k] += wv1 * u[k];
                p[2][k] += wv2 * u[k];
                p[3][k] += wv3 * u[k];
            }
        }

#pragma unroll
        for (int r = 0; r < 4; ++r)
#pragma unroll
            for (int k = 0; k < R; ++k) {
                float v = p[r][k];
#pragma unroll
                for (int off = 32; off >= 1; off >>= 1) v += __shfl_xor(v, off, 64);
                p[r][k] = v;
            }

#pragma unroll
        for (int i = 0; i < 32; ++i)
            if (lane == i) red[wave][i] = p[i / R][i % R];
        __syncthreads();

        if (t < 32) {
            float v = red[0][t] + red[1][t] + red[2][t] + red[3][t];
            G[(hi + (t >> 3)) * 8 + (t & 7)] = v;
        }
        return;
    }

    // ---- dot path: 4 rows x half the columns. Flat load batch, then FMAs.
    const int db = bid - 2;          // 0..2047
    const int row0 = (db >> 1) * 4;
    const int ch = db & 1;           // column half

    // 8 W loads: w[c][r] = W[row0+r][ch*2048 + c*1024 + 4t .. +3]
    float4 w[2][4];
#pragma unroll
    for (int c = 0; c < 2; ++c)
#pragma unroll
        for (int r = 0; r < 4; ++r)
            w[c][r] = W4[(size_t)(row0 + r) * (DIM / 4) + ch * 512 + c * 256 + t];

    // 16 A loads: aa[c][jj][h], j = ch*2048 + c*1024 + 4t + jj (lane-contig 128B)
    float4 aa[2][4][2];
#pragma unroll
    for (int c = 0; c < 2; ++c)
#pragma unroll
        for (int jj = 0; jj < 4; ++jj) {
            const int j = ch * 2048 + c * 1024 + t * 4 + jj;
            aa[c][jj][0] = A4[j * 2 + 0];
            aa[c][jj][1] = A4[j * 2 + 1];
        }

    // FMA block (no loads inside): p[r][k] += W[r][j] * A[j][k]
    float p[4][R];
#pragma unroll
    for (int r = 0; r < 4; ++r)
#pragma unroll
        for (int k = 0; k < R; ++k) p[r][k] = 0.f;

#pragma unroll
    for (int c = 0; c < 2; ++c)
#pragma unroll
        for (int jj = 0; jj < 4; ++jj) {
            const float4 alo = aa[c][jj][0];
            const float4 ahi = aa[c][jj][1];
#pragma unroll
            for (int r = 0; r < 4; ++r) {
                const float wv = ((const float*)&w[c][r])[jj];
                p[r][0] += wv * alo.x; p[r][1] += wv * alo.y;
                p[r][2] += wv * alo.z; p[r][3] += wv * alo.w;
                p[r][4] += wv * ahi.x; p[r][5] += wv * ahi.y;
                p[r][6] += wv * ahi.z; p[r][7] += wv * ahi.w;
            }
        }

#pragma unroll
    for (int r = 0; r < 4; ++r)
#pragma unroll
        for (int k = 0; k < R; ++k) {
            float v = p[r][k];
#pragma unroll
            for (int off = 32; off >= 1; off >>= 1) v += __shfl_xor(v, off, 64);
            p[r][k] = v;
        }

#pragma unroll
    for (int i = 0; i < 32; ++i)
        if (lane == i) red[wave][i] = p[i / R][i % R];
    __syncthreads();

    if (t < 32) {
        float v = red[0][t] + red[1][t] + red[2][t] + red[3][t];
        P2[((size_t)(row0 + (t >> 3)) * 2 + ch) * R + (t & 7)] = v;
    }
}

// ---------------------------------------------------------------------------
// K2: out = W - (2 (P0+P1) G^{-1}) . A^T.  2048 blocks x 256 threads.
// Wave 0 inverts G (8x8 Gauss-Jordan) hidden under A-fragment loads.
// ---------------------------------------------------------------------------
__global__ __launch_bounds__(256, 4) void apply_kernel(const float* __restrict__ W,
                                                       const float* __restrict__ A,
                                                       const float* __restrict__ G,
                                                       const float* __restrict__ P2,
                                                       float* __restrict__ out) {
    __shared__ float sb[64];       // Sinv = G^{-1}
    __shared__ float tsh[32][8];

    const int t = threadIdx.x;
    const int wave = t >> 6, lane = t & 63;
    const int bid = blockIdx.x;
    const int tr = bid >> 4;        // 128 row-tiles of 32
    const int tc = bid & 15;        // 16 col-tiles of 256
    const int c4 = tc * 64 + lane;  // float4 column index [0,1024)

    const float4* A4 = (const float4*)A;
    const float4* W4 = (const float4*)W;
    float4* O4 = (float4*)out;

    // issue A-fragment loads first (independent, hides the GJ below)
    float4 alo[4], ahi[4];
#pragma unroll
    for (int jj = 0; jj < 4; ++jj) {
        const int j = c4 * 4 + jj;
        alo[jj] = A4[j * 2 + 0];
        ahi[jj] = A4[j * 2 + 1];
    }

    if (wave == 0) {
        const int r_ = lane >> 3, c_ = lane & 7;
        float M = G[lane];
        float E = (r_ == c_) ? 1.f : 0.f;
        // Gauss-Jordan, no pivoting (G is SPD, kappa ~ 1)
#pragma unroll
        for (int k = 0; k < R; ++k) {
            float piv  = __shfl(M, k * 8 + k, 64);
            float pinv = 1.0f / piv;
            float Mkc  = __shfl(M, k * 8 + c_, 64) * pinv;
            float Ekc  = __shfl(E, k * 8 + c_, 64) * pinv;
            float Mrk  = __shfl(M, r_ * 8 + k, 64);
            bool  isk  = (r_ == k);
            M = isk ? Mkc : (M - Mrk * Mkc);
            E = isk ? Ekc : (E - Mrk * Ekc);
        }
        sb[lane] = E;
    }
    __syncthreads();

    // one t-value per thread: t[r][k] = 2 * sum_m Sinv[k][m] * (P0+P1)[row][m]
    {
        const int r = t >> 3, k = t & 7;
        const int row = tr * 32 + r;
        const float* p0 = &P2[(size_t)row * 2 * R];
        float a = 0.f;
#pragma unroll
        for (int m = 0; m < R; ++m) a += sb[k * 8 + m] * (p0[m] + p0[R + m]);
        tsh[r][k] = 2.0f * a;
    }
    __syncthreads();

    const int lr0 = wave * 8;
#pragma unroll
    for (int rr = 0; rr < 8; ++rr) {
        const int row = tr * 32 + lr0 + rr;
        const float* tv = &tsh[lr0 + rr][0];
        float t0 = tv[0], t1 = tv[1], t2 = tv[2], t3 = tv[3];
        float t4 = tv[4], t5 = tv[5], t6 = tv[6], t7 = tv[7];
        float4 w4 = W4[(size_t)row * (DIM / 4) + c4];
        float o[4];
#pragma unroll
        for (int jj = 0; jj < 4; ++jj) {
            float d = t0 * alo[jj].x + t1 * alo[jj].y +
                      t2 * alo[jj].z + t3 * alo[jj].w +
                      t4 * ahi[jj].x + t5 * ahi[jj].y +
                      t6 * ahi[jj].z + t7 * ahi[jj].w;
            o[jj] = ((const float*)&w4)[jj] - d;
        }
        O4[(size_t)row * (DIM / 4) + c4] = make_float4(o[0], o[1], o[2], o[3]);
    }
}

extern "C" void kernel_launch(void* const* d_in, const int* in_sizes, int n_in,
                              void* d_out, int out_size, void* d_ws, size_t ws_size,
                              hipStream_t stream) {
    const float* W = (const float*)d_in[0];    // [4096][4096] f32
    const float* A = (const float*)d_in[1];    // [4096][8]    f32
    float* out = (float*)d_out;                // [4096][4096] f32
    float* G = (float*)d_ws;                   // 64 floats (8x8 Gram)
    float* P2 = (float*)d_ws + P_OFF;          // 4096*2*8 floats

    dot_kernel<<<2 * (DIM / 4) + 2, 256, 0, stream>>>(W, A, G, P2);
    apply_kernel<<<2048, 256, 0, stream>>>(W, A, G, P2, out);
}